// Round 3
// baseline (2263.448 us; speedup 1.0000x reference)
//
#include <hip/hip_runtime.h>

// Decoder: h = relu(x @ W1 + b1); out = clamp(0.25*(h @ W2 + b2) + 0.5, 0, 1)
// B=262144, F=16, H=24, NOUT=784. fp32. Memory-bound: 822 MB output write.
//
// Round-1 lesson: keep W2 columns in VGPRs, loaded adjacent to use (spill = 4GB scratch).
// Round-2 lesson: (256,2) left only 2 waves/SIMD; LDS latency + store backpressure
// not hidden -> 4.0 TB/s. Force <=128 VGPR for 4 waves/SIMD; pre-scale W2 by 0.25
// and fold bias so the epilogue is a pure clamp (v_med3).

#define THREADS 256
#define ROWS_PER_BLOCK 256
#define F 16
#define H 24
#define NOUT 784
#define NCHUNK (NOUT / 4)   // 196 float4 column-chunks per row

__launch_bounds__(THREADS, 4)
__global__ void decoder_kernel(const float* __restrict__ x,
                               const float* __restrict__ W1,
                               const float* __restrict__ b1,
                               const float* __restrict__ W2,
                               const float* __restrict__ b2,
                               float* __restrict__ out) {
    __shared__ float w1t[H][F];                 // W1 transposed: w1t[j][i]
    __shared__ float b1s[H];
    __shared__ float hbuf[ROWS_PER_BLOCK][H];   // 24 KB

    const int tid  = threadIdx.x;
    const int row0 = blockIdx.x * ROWS_PER_BLOCK;

    // ---- stage W1^T and b1 into LDS
    for (int idx = tid; idx < F * H; idx += THREADS) {
        const int i = idx / H, j = idx % H;     // W1 is [F][H] row-major
        w1t[j][i] = W1[idx];
    }
    if (tid < H) b1s[tid] = b1[tid];

    // ---- load this thread's x row (16 floats = 4 x float4)
    float4 xv[4];
    {
        const float* xr = x + (size_t)(row0 + tid) * F;
        #pragma unroll
        for (int q = 0; q < 4; ++q)
            xv[q] = *reinterpret_cast<const float4*>(&xr[q * 4]);
    }

    __syncthreads();

    // ---- phase 1: h = relu(x @ W1 + b1) for row (row0 + tid)
    #pragma unroll
    for (int q6 = 0; q6 < 6; ++q6) {
        float hv[4];
        #pragma unroll
        for (int jj = 0; jj < 4; ++jj) {
            const int j = q6 * 4 + jj;
            float acc = b1s[j];
            #pragma unroll
            for (int q = 0; q < 4; ++q) {
                const float4 wv = *reinterpret_cast<const float4*>(&w1t[j][q * 4]);
                acc = fmaf(xv[q].x, wv.x, acc);
                acc = fmaf(xv[q].y, wv.y, acc);
                acc = fmaf(xv[q].z, wv.z, acc);
                acc = fmaf(xv[q].w, wv.w, acc);
            }
            hv[jj] = fmaxf(acc, 0.0f);
        }
        *reinterpret_cast<float4*>(&hbuf[tid][q6 * 4]) =
            make_float4(hv[0], hv[1], hv[2], hv[3]);
    }

    __syncthreads();

    // ---- phase 2: thread owns output columns [c0, c0+3] for all 256 rows.
    // W2 pre-scaled by 0.25, bias folded to 0.25*b2+0.5: out = clamp(acc, 0, 1).
    const int  cc = (tid < NCHUNK) ? tid : (NCHUNK - 1);   // clamp, no branch
    const int  c0 = cc * 4;
    float4 w2r[H];
    #pragma unroll
    for (int k = 0; k < H; ++k) {
        float4 w = *reinterpret_cast<const float4*>(&W2[k * NOUT + c0]);
        w.x *= 0.25f; w.y *= 0.25f; w.z *= 0.25f; w.w *= 0.25f;
        w2r[k] = w;
    }
    float4 b2v = *reinterpret_cast<const float4*>(&b2[c0]);
    b2v.x = fmaf(b2v.x, 0.25f, 0.5f);
    b2v.y = fmaf(b2v.y, 0.25f, 0.5f);
    b2v.z = fmaf(b2v.z, 0.25f, 0.5f);
    b2v.w = fmaf(b2v.w, 0.25f, 0.5f);

    if (tid < NCHUNK) {
        float* outp = out + (size_t)row0 * NOUT + c0;
        for (int r = 0; r < ROWS_PER_BLOCK; ++r) {
            float4 acc = b2v;
            #pragma unroll
            for (int q = 0; q < 6; ++q) {
                // uniform address across the wave -> LDS broadcast, no conflict
                const float4 hv = *reinterpret_cast<const float4*>(&hbuf[r][q * 4]);
                const float h0 = hv.x, h1 = hv.y, h2 = hv.z, h3 = hv.w;
                acc.x = fmaf(h0, w2r[q * 4 + 0].x, acc.x);
                acc.y = fmaf(h0, w2r[q * 4 + 0].y, acc.y);
                acc.z = fmaf(h0, w2r[q * 4 + 0].z, acc.z);
                acc.w = fmaf(h0, w2r[q * 4 + 0].w, acc.w);
                acc.x = fmaf(h1, w2r[q * 4 + 1].x, acc.x);
                acc.y = fmaf(h1, w2r[q * 4 + 1].y, acc.y);
                acc.z = fmaf(h1, w2r[q * 4 + 1].z, acc.z);
                acc.w = fmaf(h1, w2r[q * 4 + 1].w, acc.w);
                acc.x = fmaf(h2, w2r[q * 4 + 2].x, acc.x);
                acc.y = fmaf(h2, w2r[q * 4 + 2].y, acc.y);
                acc.z = fmaf(h2, w2r[q * 4 + 2].z, acc.z);
                acc.w = fmaf(h2, w2r[q * 4 + 2].w, acc.w);
                acc.x = fmaf(h3, w2r[q * 4 + 3].x, acc.x);
                acc.y = fmaf(h3, w2r[q * 4 + 3].y, acc.y);
                acc.z = fmaf(h3, w2r[q * 4 + 3].z, acc.z);
                acc.w = fmaf(h3, w2r[q * 4 + 3].w, acc.w);
            }
            float4 o;
            o.x = fminf(fmaxf(acc.x, 0.f), 1.f);
            o.y = fminf(fmaxf(acc.y, 0.f), 1.f);
            o.z = fminf(fmaxf(acc.z, 0.f), 1.f);
            o.w = fminf(fmaxf(acc.w, 0.f), 1.f);
            *reinterpret_cast<float4*>(outp) = o;
            outp += NOUT;
        }
    }
}

extern "C" void kernel_launch(void* const* d_in, const int* in_sizes, int n_in,
                              void* d_out, int out_size, void* d_ws, size_t ws_size,
                              hipStream_t stream) {
    const float* x  = (const float*)d_in[0];
    const float* W1 = (const float*)d_in[1];
    const float* b1 = (const float*)d_in[2];
    const float* W2 = (const float*)d_in[3];
    const float* b2 = (const float*)d_in[4];
    float* out = (float*)d_out;

    const int B = in_sizes[0] / F;              // 262144
    const int grid = B / ROWS_PER_BLOCK;        // 1024
    decoder_kernel<<<grid, THREADS, 0, stream>>>(x, W1, b1, W2, b2, out);
}

// Round 4
// 1981.910 us; speedup vs baseline: 1.1421x; 1.1421x over previous
//
#include <hip/hip_runtime.h>

// Decoder: h = relu(x @ W1 + b1); out = clamp(0.25*(h @ W2 + b2) + 0.5, 0, 1)
// B=262144, F=16, H=24, NOUT=784. fp32. Memory-bound: 822 MB output write.
//
// Round-1 lesson: W2 cols must live in VGPRs, loaded adjacent to use (else 4GB scratch).
// Round-3 lesson: (256,4) cap=128 made the allocator dump w2r entirely (VGPR=64,
//   FETCH 6.2GB). The w2r approach needs a cap well above ~130.
// Round-2 baseline: (256,2) = 208 us, ~63% of store BW (only 8 waves/CU).
// This round: (256,3) -> cap ~170 VGPR, 12 waves/CU. Single change vs round 2.

#define THREADS 256
#define ROWS_PER_BLOCK 256
#define F 16
#define H 24
#define NOUT 784
#define NCHUNK (NOUT / 4)   // 196 float4 column-chunks per row

__launch_bounds__(THREADS, 3)
__global__ void decoder_kernel(const float* __restrict__ x,
                               const float* __restrict__ W1,
                               const float* __restrict__ b1,
                               const float* __restrict__ W2,
                               const float* __restrict__ b2,
                               float* __restrict__ out) {
    __shared__ float w1t[H][F];                 // W1 transposed: w1t[j][i]
    __shared__ float b1s[H];
    __shared__ float hbuf[ROWS_PER_BLOCK][H];   // 24 KB

    const int tid  = threadIdx.x;
    const int row0 = blockIdx.x * ROWS_PER_BLOCK;

    // ---- stage W1^T and b1 into LDS
    for (int idx = tid; idx < F * H; idx += THREADS) {
        const int i = idx / H, j = idx % H;     // W1 is [F][H] row-major
        w1t[j][i] = W1[idx];
    }
    if (tid < H) b1s[tid] = b1[tid];

    // ---- load this thread's x row (16 floats = 4 x float4)
    float4 xv[4];
    {
        const float* xr = x + (size_t)(row0 + tid) * F;
        #pragma unroll
        for (int q = 0; q < 4; ++q)
            xv[q] = *reinterpret_cast<const float4*>(&xr[q * 4]);
    }

    __syncthreads();

    // ---- phase 1: h = relu(x @ W1 + b1) for row (row0 + tid)
    #pragma unroll
    for (int q6 = 0; q6 < 6; ++q6) {
        float hv[4];
        #pragma unroll
        for (int jj = 0; jj < 4; ++jj) {
            const int j = q6 * 4 + jj;
            float acc = b1s[j];
            #pragma unroll
            for (int q = 0; q < 4; ++q) {
                const float4 wv = *reinterpret_cast<const float4*>(&w1t[j][q * 4]);
                acc = fmaf(xv[q].x, wv.x, acc);
                acc = fmaf(xv[q].y, wv.y, acc);
                acc = fmaf(xv[q].z, wv.z, acc);
                acc = fmaf(xv[q].w, wv.w, acc);
            }
            hv[jj] = fmaxf(acc, 0.0f);
        }
        *reinterpret_cast<float4*>(&hbuf[tid][q6 * 4]) =
            make_float4(hv[0], hv[1], hv[2], hv[3]);
    }

    __syncthreads();

    // ---- phase 2: thread owns output columns [c0, c0+3] for all 256 rows.
    // W2 pre-scaled by 0.25, bias folded to 0.25*b2+0.5: out = clamp(acc, 0, 1).
    const int  cc = (tid < NCHUNK) ? tid : (NCHUNK - 1);   // clamp, no branch
    const int  c0 = cc * 4;
    float4 w2r[H];
    #pragma unroll
    for (int k = 0; k < H; ++k) {
        float4 w = *reinterpret_cast<const float4*>(&W2[k * NOUT + c0]);
        w.x *= 0.25f; w.y *= 0.25f; w.z *= 0.25f; w.w *= 0.25f;
        w2r[k] = w;
    }
    float4 b2v = *reinterpret_cast<const float4*>(&b2[c0]);
    b2v.x = fmaf(b2v.x, 0.25f, 0.5f);
    b2v.y = fmaf(b2v.y, 0.25f, 0.5f);
    b2v.z = fmaf(b2v.z, 0.25f, 0.5f);
    b2v.w = fmaf(b2v.w, 0.25f, 0.5f);

    if (tid < NCHUNK) {
        float* outp = out + (size_t)row0 * NOUT + c0;
        for (int r = 0; r < ROWS_PER_BLOCK; ++r) {
            float4 acc = b2v;
            #pragma unroll
            for (int q = 0; q < 6; ++q) {
                // uniform address across the wave -> LDS broadcast, no conflict
                const float4 hv = *reinterpret_cast<const float4*>(&hbuf[r][q * 4]);
                const float h0 = hv.x, h1 = hv.y, h2 = hv.z, h3 = hv.w;
                acc.x = fmaf(h0, w2r[q * 4 + 0].x, acc.x);
                acc.y = fmaf(h0, w2r[q * 4 + 0].y, acc.y);
                acc.z = fmaf(h0, w2r[q * 4 + 0].z, acc.z);
                acc.w = fmaf(h0, w2r[q * 4 + 0].w, acc.w);
                acc.x = fmaf(h1, w2r[q * 4 + 1].x, acc.x);
                acc.y = fmaf(h1, w2r[q * 4 + 1].y, acc.y);
                acc.z = fmaf(h1, w2r[q * 4 + 1].z, acc.z);
                acc.w = fmaf(h1, w2r[q * 4 + 1].w, acc.w);
                acc.x = fmaf(h2, w2r[q * 4 + 2].x, acc.x);
                acc.y = fmaf(h2, w2r[q * 4 + 2].y, acc.y);
                acc.z = fmaf(h2, w2r[q * 4 + 2].z, acc.z);
                acc.w = fmaf(h2, w2r[q * 4 + 2].w, acc.w);
                acc.x = fmaf(h3, w2r[q * 4 + 3].x, acc.x);
                acc.y = fmaf(h3, w2r[q * 4 + 3].y, acc.y);
                acc.z = fmaf(h3, w2r[q * 4 + 3].z, acc.z);
                acc.w = fmaf(h3, w2r[q * 4 + 3].w, acc.w);
            }
            float4 o;
            o.x = fminf(fmaxf(acc.x, 0.f), 1.f);
            o.y = fminf(fmaxf(acc.y, 0.f), 1.f);
            o.z = fminf(fmaxf(acc.z, 0.f), 1.f);
            o.w = fminf(fmaxf(acc.w, 0.f), 1.f);
            *reinterpret_cast<float4*>(outp) = o;
            outp += NOUT;
        }
    }
}

extern "C" void kernel_launch(void* const* d_in, const int* in_sizes, int n_in,
                              void* d_out, int out_size, void* d_ws, size_t ws_size,
                              hipStream_t stream) {
    const float* x  = (const float*)d_in[0];
    const float* W1 = (const float*)d_in[1];
    const float* b1 = (const float*)d_in[2];
    const float* W2 = (const float*)d_in[3];
    const float* b2 = (const float*)d_in[4];
    float* out = (float*)d_out;

    const int B = in_sizes[0] / F;              // 262144
    const int grid = B / ROWS_PER_BLOCK;        // 1024
    decoder_kernel<<<grid, THREADS, 0, stream>>>(x, W1, b1, W2, b2, out);
}

// Round 6
// 182.541 us; speedup vs baseline: 12.3997x; 10.8574x over previous
//
#include <hip/hip_runtime.h>

// Decoder: h = relu(x @ W1 + b1); out = clamp(0.25*(h @ W2 + b2) + 0.5, 0, 1)
// B=262144, F=16, H=24, NOUT=784. Memory-bound: 822 MB fp32 output write.
//
// History:
//  R1/R3/R4: 96-VGPR fp32 W2 array spills under ANY launch_bounds cap
//            ((256,3) cap~168 still collapsed to VGPR=84, FETCH 2.9-6.2 GB).
//  R2: (256,2) kept regs -> 208 us, but phase-2 LDS h-reads ~123 us/CU
//      (6 ds_read_b128/row/wave) nearly equal the 130 us HBM store floor.
//  R5: cvt_pkrtz returns __fp16x2, not _Float16x2 -> compile fail. Fix:
//      keep packed data as u32, bit_cast to _Float16x2 only at fdot2 site.
//  This round (same theory as R4): f16 packed dot2 (v_dot2_f32_f16, fp32 acc).
//    - W2 regs halve: 48 u32 VGPRs -> survives (256,3) (12 waves/CU)
//    - hbuf packed half2: 3 ds_read_b128/row/wave -> LDS ~61 us/CU
//    - VALU halves: 48 dot2/row instead of 96 fma
//  f16 error ~1e-3 << 0.017 threshold.

typedef _Float16 h2_t __attribute__((ext_vector_type(2)));

static __device__ __forceinline__ unsigned int pk_h2(float lo, float hi) {
    return __builtin_bit_cast(unsigned int, __builtin_amdgcn_cvt_pkrtz(lo, hi));
}

#if __has_builtin(__builtin_amdgcn_fdot2)
static __device__ __forceinline__ float fdot2u(unsigned int a, unsigned int b, float c) {
    return __builtin_amdgcn_fdot2(__builtin_bit_cast(h2_t, a),
                                  __builtin_bit_cast(h2_t, b), c, false);
}
#else
static __device__ __forceinline__ float fdot2u(unsigned int a, unsigned int b, float c) {
    const h2_t av = __builtin_bit_cast(h2_t, a);
    const h2_t bv = __builtin_bit_cast(h2_t, b);
    return fmaf((float)av.y, (float)bv.y, fmaf((float)av.x, (float)bv.x, c));
}
#endif

#define THREADS 256
#define ROWS_PER_BLOCK 256
#define F 16
#define H 24
#define KP 12               // half2 pairs along the K=24 reduction
#define NOUT 784
#define NCHUNK (NOUT / 4)   // 196 float4 column-chunks per row

__launch_bounds__(THREADS, 3)
__global__ void decoder_kernel(const float* __restrict__ x,
                               const float* __restrict__ W1,
                               const float* __restrict__ b1,
                               const float* __restrict__ W2,
                               const float* __restrict__ b2,
                               float* __restrict__ out) {
    __shared__ float w1t[H][F];                       // W1^T
    __shared__ float b1s[H];
    __shared__ unsigned int hbuf[ROWS_PER_BLOCK][KP]; // h packed half2, 12 KB

    const int tid  = threadIdx.x;
    const int row0 = blockIdx.x * ROWS_PER_BLOCK;

    // ---- stage W1^T and b1 into LDS
    for (int idx = tid; idx < F * H; idx += THREADS) {
        const int i = idx / H, j = idx % H;           // W1 is [F][H] row-major
        w1t[j][i] = W1[idx];
    }
    if (tid < H) b1s[tid] = b1[tid];

    // ---- load this thread's x row (16 floats = 4 x float4)
    float4 xv[4];
    {
        const float* xr = x + (size_t)(row0 + tid) * F;
        #pragma unroll
        for (int q = 0; q < 4; ++q)
            xv[q] = *reinterpret_cast<const float4*>(&xr[q * 4]);
    }

    __syncthreads();

    // ---- phase 1: h = relu(x @ W1 + b1); pack pairs to half2; one b128
    //      LDS write per 8 outputs.
    #pragma unroll
    for (int g = 0; g < 3; ++g) {
        float hj[8];
        #pragma unroll
        for (int jj = 0; jj < 8; ++jj) {
            const int j = g * 8 + jj;
            float acc = b1s[j];
            #pragma unroll
            for (int q = 0; q < 4; ++q) {
                const float4 wv = *reinterpret_cast<const float4*>(&w1t[j][q * 4]);
                acc = fmaf(xv[q].x, wv.x, acc);
                acc = fmaf(xv[q].y, wv.y, acc);
                acc = fmaf(xv[q].z, wv.z, acc);
                acc = fmaf(xv[q].w, wv.w, acc);
            }
            hj[jj] = fmaxf(acc, 0.0f);
        }
        uint4 p;
        p.x = pk_h2(hj[0], hj[1]);
        p.y = pk_h2(hj[2], hj[3]);
        p.z = pk_h2(hj[4], hj[5]);
        p.w = pk_h2(hj[6], hj[7]);
        *reinterpret_cast<uint4*>(&hbuf[tid][g * 4]) = p;
    }

    __syncthreads();

    // ---- phase 2: thread owns output cols [c0, c0+3] for all 256 rows.
    // W2 packed to half2 (pre-scaled by 0.25), loaded adjacent to use:
    // 12 kp x 4 cols = 48 u32 VGPRs. Bias folded: out = clamp(acc, 0, 1).
    const int cc = (tid < NCHUNK) ? tid : (NCHUNK - 1);  // clamp, no branch
    const int c0 = cc * 4;

    unsigned int w2p[KP][4];
    #pragma unroll
    for (int kp = 0; kp < KP; ++kp) {
        const float4 a = *reinterpret_cast<const float4*>(&W2[(2 * kp + 0) * NOUT + c0]);
        const float4 b = *reinterpret_cast<const float4*>(&W2[(2 * kp + 1) * NOUT + c0]);
        w2p[kp][0] = pk_h2(0.25f * a.x, 0.25f * b.x);
        w2p[kp][1] = pk_h2(0.25f * a.y, 0.25f * b.y);
        w2p[kp][2] = pk_h2(0.25f * a.z, 0.25f * b.z);
        w2p[kp][3] = pk_h2(0.25f * a.w, 0.25f * b.w);
    }
    float4 b2v = *reinterpret_cast<const float4*>(&b2[c0]);
    b2v.x = fmaf(b2v.x, 0.25f, 0.5f);
    b2v.y = fmaf(b2v.y, 0.25f, 0.5f);
    b2v.z = fmaf(b2v.z, 0.25f, 0.5f);
    b2v.w = fmaf(b2v.w, 0.25f, 0.5f);

    if (tid < NCHUNK) {
        float* outp = out + (size_t)row0 * NOUT + c0;
        for (int r = 0; r < ROWS_PER_BLOCK; ++r) {
            // h row: 3 uniform-address (broadcast) b128 reads = 12 half2
            const uint4 h0 = *reinterpret_cast<const uint4*>(&hbuf[r][0]);
            const uint4 h1 = *reinterpret_cast<const uint4*>(&hbuf[r][4]);
            const uint4 h2 = *reinterpret_cast<const uint4*>(&hbuf[r][8]);
            unsigned int hw[KP];
            hw[0] = h0.x; hw[1]  = h0.y; hw[2]  = h0.z; hw[3]  = h0.w;
            hw[4] = h1.x; hw[5]  = h1.y; hw[6]  = h1.z; hw[7]  = h1.w;
            hw[8] = h2.x; hw[9]  = h2.y; hw[10] = h2.z; hw[11] = h2.w;

            float4 acc = b2v;
            #pragma unroll
            for (int kp = 0; kp < KP; ++kp) {
                acc.x = fdot2u(hw[kp], w2p[kp][0], acc.x);
                acc.y = fdot2u(hw[kp], w2p[kp][1], acc.y);
                acc.z = fdot2u(hw[kp], w2p[kp][2], acc.z);
                acc.w = fdot2u(hw[kp], w2p[kp][3], acc.w);
            }
            float4 o;
            o.x = fminf(fmaxf(acc.x, 0.f), 1.f);
            o.y = fminf(fmaxf(acc.y, 0.f), 1.f);
            o.z = fminf(fmaxf(acc.z, 0.f), 1.f);
            o.w = fminf(fmaxf(acc.w, 0.f), 1.f);
            *reinterpret_cast<float4*>(outp) = o;
            outp += NOUT;
        }
    }
}

extern "C" void kernel_launch(void* const* d_in, const int* in_sizes, int n_in,
                              void* d_out, int out_size, void* d_ws, size_t ws_size,
                              hipStream_t stream) {
    const float* x  = (const float*)d_in[0];
    const float* W1 = (const float*)d_in[1];
    const float* b1 = (const float*)d_in[2];
    const float* W2 = (const float*)d_in[3];
    const float* b2 = (const float*)d_in[4];
    float* out = (float*)d_out;

    const int B = in_sizes[0] / F;              // 262144
    const int grid = B / ROWS_PER_BLOCK;        // 1024
    decoder_kernel<<<grid, THREADS, 0, stream>>>(x, W1, b1, W2, b2, out);
}